// Round 5
// baseline (1264.964 us; speedup 1.0000x reference)
//
#include <hip/hip_runtime.h>
#include <hip/hip_bf16.h>

#define LL 128
#define BB 32
#define EE 128
#define HH 256
#define NHH 8
#define G3 768   // 3*H
#define IN0 130
#define ETA 100
#define F1 168
#define CLSIN 2304  // 8*256 + 256

typedef _Float16 half_t;
typedef __attribute__((ext_vector_type(2))) _Float16 half2v;
typedef __attribute__((ext_vector_type(4))) _Float16 half4v;
typedef __attribute__((ext_vector_type(8))) _Float16 f16x8;
typedef __attribute__((ext_vector_type(4))) float f32x4;

#if defined(__has_builtin)
#if __has_builtin(__builtin_amdgcn_fdot2)
#define HAVE_FDOT2 1
#endif
#endif

__device__ __forceinline__ float fdot2f(half2v a, half2v b, float c) {
#ifdef HAVE_FDOT2
  return __builtin_amdgcn_fdot2(a, b, c, false);
#else
  return c + (float)a.x * (float)b.x + (float)a.y * (float)b.y;
#endif
}

// LDS-only barrier: skip the compiler's vmcnt(0) drain (no cross-thread
// global-memory dependencies at our barriers).
#define BARRIER_LDS() __asm__ volatile("s_waitcnt lgkmcnt(0)\n\ts_barrier" ::: "memory")

__device__ __forceinline__ float sigmoidf_(float x) { return 1.0f / (1.0f + __expf(-x)); }
__device__ __forceinline__ float tanhf_(float x) { return 1.0f - 2.0f / (__expf(2.0f * x) + 1.0f); }

// ---------------------------------------------------------------------------
// prep: weight repack fp32 -> f16 (weights ~N(0,0.05^2): f16 rel err 5e-4)
// ---------------------------------------------------------------------------
__global__ void prep_kernel(
    const float* __restrict__ Wa0, const float* __restrict__ Wih0,
    const float* __restrict__ Wih1, const float* __restrict__ Whh0,
    const float* __restrict__ Whh1,
    half_t* __restrict__ Wa0Ta, half_t* __restrict__ Wa0Tb,
    half2v* __restrict__ Wih0T2, half2v* __restrict__ Wih1T2,
    half_t* __restrict__ Whh0h, half_t* __restrict__ Whh1h)
{
  int idx = blockIdx.x * blockDim.x + threadIdx.x;
  const int n1 = 16384, n2 = 16384, n3 = 65 * 768, n4 = 128 * 768, n5 = 196608;
  if (idx < n1) {
    int d = idx >> 7, k = idx & 127;
    Wa0Ta[idx] = (half_t)Wa0[k * 256 + d];
  } else if ((idx -= n1) < n2) {
    int d = idx >> 7, k = idx & 127;
    Wa0Tb[idx] = (half_t)Wa0[k * 256 + 128 + d];
  } else if ((idx -= n2) < n3) {
    int d2 = idx / 768, r = idx % 768;
    half2v w; w.x = (half_t)Wih0[r * IN0 + 2 * d2]; w.y = (half_t)Wih0[r * IN0 + 2 * d2 + 1];
    Wih0T2[idx] = w;
  } else if ((idx -= n3) < n4) {
    int d2 = idx / 768, r = idx % 768;
    half2v w; w.x = (half_t)Wih1[r * HH + 2 * d2]; w.y = (half_t)Wih1[r * HH + 2 * d2 + 1];
    Wih1T2[idx] = w;
  } else if ((idx -= n4) < n5) {
    Whh0h[idx] = (half_t)Whh0[idx];
  } else if ((idx -= n5) < n5) {
    Whh1h[idx] = (half_t)Whh1[idx];
  }
}

// ---------------------------------------------------------------------------
// embed gather + U/V factors of the pairwise attention
// ---------------------------------------------------------------------------
__global__ void embed_uv_kernel(
    const int* __restrict__ node,             // [L*B]
    const float* __restrict__ table,          // [20001][128]
    const half_t* __restrict__ Wa0Ta,         // [128 d][128 k]
    const half_t* __restrict__ Wa0Tb,
    const float* __restrict__ ba0,            // [128]
    half2v* __restrict__ e_h2,                // [L*B][64]
    float* __restrict__ U,
    float* __restrict__ V)
{
  int lb = blockIdx.x;
  int k = threadIdx.x;  // 128
  __shared__ float es[EE];
  int n = node[lb];
  float ev = table[(size_t)n * EE + k];
  es[k] = ev;
  __syncthreads();
  if (k < 64) {
    half2v p; p.x = (half_t)es[2 * k]; p.y = (half_t)es[2 * k + 1];
    e_h2[(size_t)lb * 64 + k] = p;
  }
  float u = 0.f, v = ba0[k];
  #pragma unroll 8
  for (int d = 0; d < EE; ++d) {
    float x = es[d];
    u += (float)Wa0Ta[d * EE + k] * x;
    v += (float)Wa0Tb[d * EE + k] * x;
  }
  U[(size_t)lb * EE + k] = u;
  V[(size_t)lb * EE + k] = v;
}

// ---------------------------------------------------------------------------
// w_pre[i,b,h] = sum_j sum_k Wa1[h,k] * relu(U[j,b,k]+V[i,b,k]) + L*ba1[h]
// ---------------------------------------------------------------------------
__global__ __launch_bounds__(128) void attn_w_kernel(
    const float* __restrict__ U, const float* __restrict__ V,
    const float* __restrict__ Wa1,  // [8][128]
    const float* __restrict__ ba1,  // [8]
    float* __restrict__ wpre)       // [L][B][8]
{
  int ig = blockIdx.x >> 5;
  int b = blockIdx.x & 31;
  int i0 = ig * 4;
  int k = threadIdx.x;  // 128
  float vk[4];
  #pragma unroll
  for (int ii = 0; ii < 4; ++ii) vk[ii] = V[((size_t)(i0 + ii) * BB + b) * EE + k];
  float wa[NHH], acc[4][NHH];
  #pragma unroll
  for (int h = 0; h < NHH; ++h) wa[h] = Wa1[h * EE + k];
  #pragma unroll
  for (int ii = 0; ii < 4; ++ii)
    #pragma unroll
    for (int h = 0; h < NHH; ++h) acc[ii][h] = 0.f;
  for (int j = 0; j < LL; ++j) {
    float u = U[((size_t)j * BB + b) * EE + k];
    #pragma unroll
    for (int ii = 0; ii < 4; ++ii) {
      float tv = fmaxf(u + vk[ii], 0.f);
      #pragma unroll
      for (int h = 0; h < NHH; ++h) acc[ii][h] += wa[h] * tv;
    }
  }
  __shared__ float part[2][32];
  int wave = k >> 6, lane = k & 63;
  #pragma unroll
  for (int ii = 0; ii < 4; ++ii)
    #pragma unroll
    for (int h = 0; h < NHH; ++h) {
      float a = acc[ii][h];
      #pragma unroll
      for (int off = 32; off > 0; off >>= 1) a += __shfl_xor(a, off, 64);
      if (lane == 0) part[wave][ii * 8 + h] = a;
    }
  __syncthreads();
  if (k < 32) {
    int ii = k >> 3, h = k & 7;
    float w = part[0][k] + part[1][k] + (float)LL * ba1[h];
    wpre[((size_t)(i0 + ii) * BB + b) * NHH + h] = w;
  }
}

// softmax over l of (w * mask): masked entries become 0 and STAY in the softmax
__global__ void attn_softmax_kernel(
    const float* __restrict__ wpre, const int* __restrict__ slen,
    float* __restrict__ wsoft)
{
  int b = blockIdx.x >> 3;
  int h = blockIdx.x & 7;
  int l = threadIdx.x;  // 128
  int len = slen[b];
  float x = wpre[((size_t)l * BB + b) * NHH + h];
  float xv = (l < len) ? x : 0.f;
  float m = xv;
  #pragma unroll
  for (int off = 32; off > 0; off >>= 1) m = fmaxf(m, __shfl_xor(m, off, 64));
  __shared__ float sm[2], ss[2];
  int wave = l >> 6;
  if ((l & 63) == 0) sm[wave] = m;
  __syncthreads();
  m = fmaxf(sm[0], sm[1]);
  float e = __expf(xv - m);
  float s = e;
  #pragma unroll
  for (int off = 32; off > 0; off >>= 1) s += __shfl_xor(s, off, 64);
  if ((l & 63) == 0) ss[wave] = s;
  __syncthreads();
  s = ss[0] + ss[1];
  wsoft[((size_t)l * BB + b) * NHH + h] = e / s;
}

// ---------------------------------------------------------------------------
// gi0: [e, ts] @ Wih0.T + bih0, 8 lb per block, v_dot2 on packed pairs
// ---------------------------------------------------------------------------
__global__ __launch_bounds__(256) void gi0_kernel(
    const half2v* __restrict__ e_h2, const float* __restrict__ ts,
    const half2v* __restrict__ W2,   // [65][768]
    const float* __restrict__ bih,
    float* __restrict__ gi)
{
  int lb0 = blockIdx.x * 8;
  int tid = threadIdx.x;  // 256
  __shared__ half2v xs2[8][66];
  for (int idx = tid; idx < 512; idx += 256) {
    int q = idx >> 6, d2 = idx & 63;
    xs2[q][d2] = e_h2[(size_t)(lb0 + q) * 64 + d2];
  }
  if (tid < 8) {
    half2v t2; t2.x = (half_t)ts[(lb0 + tid) * 2]; t2.y = (half_t)ts[(lb0 + tid) * 2 + 1];
    xs2[tid][64] = t2;
  }
  __syncthreads();
  float acc[8][3];
  #pragma unroll
  for (int q = 0; q < 8; ++q) { acc[q][0] = 0.f; acc[q][1] = 0.f; acc[q][2] = 0.f; }
  for (int d2 = 0; d2 < 65; ++d2) {
    half2v w0 = W2[d2 * 768 + tid];
    half2v w1 = W2[d2 * 768 + 256 + tid];
    half2v w2 = W2[d2 * 768 + 512 + tid];
    #pragma unroll
    for (int q = 0; q < 8; ++q) {
      half2v x = xs2[q][d2];
      acc[q][0] = fdot2f(w0, x, acc[q][0]);
      acc[q][1] = fdot2f(w1, x, acc[q][1]);
      acc[q][2] = fdot2f(w2, x, acc[q][2]);
    }
  }
  float b0 = bih[tid], b1 = bih[256 + tid], b2 = bih[512 + tid];
  #pragma unroll
  for (int q = 0; q < 8; ++q) {
    float* gp = gi + (size_t)(lb0 + q) * G3;
    gp[tid] = acc[q][0] + b0; gp[256 + tid] = acc[q][1] + b1; gp[512 + tid] = acc[q][2] + b2;
  }
}

// ---------------------------------------------------------------------------
// gi1: out0 @ Wih1.T + bih1, 8 lb per block
// ---------------------------------------------------------------------------
__global__ __launch_bounds__(256) void gi1_kernel(
    const float* __restrict__ out0,  // [L*B][256]
    const half2v* __restrict__ W2,   // [128][768]
    const float* __restrict__ bih,
    float* __restrict__ gi)
{
  int lb0 = blockIdx.x * 8;
  int tid = threadIdx.x;  // 256
  __shared__ half2v xs2[8][128];
  for (int idx = tid; idx < 1024; idx += 256) {
    int q = idx >> 7, d2 = idx & 127;
    float2 v = ((const float2*)(out0 + (size_t)(lb0 + q) * HH))[d2];
    half2v x; x.x = (half_t)v.x; x.y = (half_t)v.y;
    xs2[q][d2] = x;
  }
  __syncthreads();
  float acc[8][3];
  #pragma unroll
  for (int q = 0; q < 8; ++q) { acc[q][0] = 0.f; acc[q][1] = 0.f; acc[q][2] = 0.f; }
  for (int d2 = 0; d2 < 128; ++d2) {
    half2v w0 = W2[d2 * 768 + tid];
    half2v w1 = W2[d2 * 768 + 256 + tid];
    half2v w2 = W2[d2 * 768 + 512 + tid];
    #pragma unroll
    for (int q = 0; q < 8; ++q) {
      half2v x = xs2[q][d2];
      acc[q][0] = fdot2f(w0, x, acc[q][0]);
      acc[q][1] = fdot2f(w1, x, acc[q][1]);
      acc[q][2] = fdot2f(w2, x, acc[q][2]);
    }
  }
  float b0 = bih[tid], b1 = bih[256 + tid], b2 = bih[512 + tid];
  #pragma unroll
  for (int q = 0; q < 8; ++q) {
    float* gp = gi + (size_t)(lb0 + q) * G3;
    gp[tid] = acc[q][0] + b0; gp[256 + tid] = acc[q][1] + b1; gp[512 + tid] = acc[q][2] + b2;
  }
}

// ---------------------------------------------------------------------------
// GRU scan v5 (MFMA, in-register tail): one block per batch, 512 thr = 8 waves.
//
// R4 post-mortem: MFMA matvec was correct but latency-serial (~3400 cyc/step):
// per-kc ds_read->wait->MFMA interleave, tail-sunk gi loads, gsum LDS
// round-trip with 2 barriers. v5 re-maps wave w to own ALL 3 GATES of units
// w*32..w*32+31: row-tiles tl=0,1 -> gate r rows w*32+{0,16}+m; tl=2,3 ->
// 256+...; tl=4,5 -> 512+... . After MFMA (B = h broadcast, same (kg,e)->k
// convention as A, R4-verified), lane (m,kg) holds r/z/n sums for units
// u = w*32 + j*16 + kg*4 + reg (j=0,1; reg=0..3) in C[j],C[2+j],C[4+j] —
// activation runs fully in registers (replicated over m; m==0 lanes store).
// h double-buffered in LDS -> ONE barrier per step. All 8 B-frags prefetched
// into bf[8] before the MFMA block; 6 gate-input float4 loads issued at step
// top so L2 latency hides under LDS+MFMA.
// ---------------------------------------------------------------------------
__global__ __launch_bounds__(512, 2) void gru_scan_kernel(
    const half_t* __restrict__ Whhh,         // [768][256] f16
    const float* __restrict__ bhh,           // [768]
    const float* __restrict__ gi,            // [L][B][768]
    const int* __restrict__ slen,            // [B]
    float* __restrict__ out,                 // [L][B][256]
    float* __restrict__ hT)                  // [B][256]
{
  const int b = blockIdx.x;
  const int tid = threadIdx.x;
  const int w = tid >> 6;          // wave 0..7
  const int lane = tid & 63;
  const int m = lane & 15;         // A row-in-tile / D col
  const int kg = lane >> 4;        // k-group 0..3

  __shared__ __align__(16) half_t hbuf[2][HH];

  // A-fragments: tile tl row = (tl>>1)*256 + w*32 + (tl&1)*16 + m
  f16x8 A[48];
  #pragma unroll
  for (int tl = 0; tl < 6; ++tl) {
    int row = ((tl >> 1) << 8) + w * 32 + ((tl & 1) << 4) + m;
    const half_t* wbase = Whhh + (size_t)row * HH + kg * 8;
    #pragma unroll
    for (int kc = 0; kc < 8; ++kc)
      A[tl * 8 + kc] = *(const f16x8*)(wbase + kc * 32);
  }

  const int len = slen[b];
  const int u0 = w * 32 + kg * 4;  // first owned unit (j=0)
  // biases for the 8 owned units (replicated across m)
  float4 br[2], bz[2], bn[2];
  #pragma unroll
  for (int j = 0; j < 2; ++j) {
    br[j] = *(const float4*)(bhh + u0 + j * 16);
    bz[j] = *(const float4*)(bhh + HH + u0 + j * 16);
    bn[j] = *(const float4*)(bhh + 2 * HH + u0 + j * 16);
  }
  float hold[2][4] = {{0.f, 0.f, 0.f, 0.f}, {0.f, 0.f, 0.f, 0.f}};
  if (tid < HH) { hbuf[0][tid] = (half_t)0.f; hbuf[1][tid] = (half_t)0.f; }
  __syncthreads();

  const float* gib = gi + (size_t)b * G3;
  float* outb = out + (size_t)b * HH;

  #pragma unroll 1
  for (int t = 0; t < LL; ++t) {
    const int p = t & 1;
    // gate inputs for the 8 owned units — issue FIRST (hide L2 latency)
    const float* gp = gib + (size_t)t * (BB * G3);
    float4 gr[2], gz[2], gn[2];
    #pragma unroll
    for (int j = 0; j < 2; ++j) {
      gr[j] = *(const float4*)(gp + u0 + j * 16);
      gz[j] = *(const float4*)(gp + HH + u0 + j * 16);
      gn[j] = *(const float4*)(gp + 2 * HH + u0 + j * 16);
    }
    // all 8 B-fragments up front: back-to-back ds_read_b128, one wait
    f16x8 bf[8];
    #pragma unroll
    for (int kc = 0; kc < 8; ++kc)
      bf[kc] = *(const f16x8*)&hbuf[p][kc * 32 + kg * 8];
    f32x4 C[6];
    #pragma unroll
    for (int tl = 0; tl < 6; ++tl) C[tl] = (f32x4){0.f, 0.f, 0.f, 0.f};
    #pragma unroll
    for (int kc = 0; kc < 8; ++kc)
      #pragma unroll
      for (int tl = 0; tl < 6; ++tl)
        C[tl] = __builtin_amdgcn_mfma_f32_16x16x32_f16(A[tl * 8 + kc], bf[kc], C[tl], 0, 0, 0);
    // in-register activation for 8 owned units (replicated across m lanes)
    bool valid = t < len;
    #pragma unroll
    for (int j = 0; j < 2; ++j) {
      float4 ov;
      half4v hv;
      #pragma unroll
      for (int reg = 0; reg < 4; ++reg) {
        float grv = (reg == 0 ? gr[j].x : reg == 1 ? gr[j].y : reg == 2 ? gr[j].z : gr[j].w);
        float gzv = (reg == 0 ? gz[j].x : reg == 1 ? gz[j].y : reg == 2 ? gz[j].z : gz[j].w);
        float gnv = (reg == 0 ? gn[j].x : reg == 1 ? gn[j].y : reg == 2 ? gn[j].z : gn[j].w);
        float brv = (reg == 0 ? br[j].x : reg == 1 ? br[j].y : reg == 2 ? br[j].z : br[j].w);
        float bzv = (reg == 0 ? bz[j].x : reg == 1 ? bz[j].y : reg == 2 ? bz[j].z : bz[j].w);
        float bnv = (reg == 0 ? bn[j].x : reg == 1 ? bn[j].y : reg == 2 ? bn[j].z : bn[j].w);
        float r_ = sigmoidf_(grv + C[j][reg] + brv);
        float z_ = sigmoidf_(gzv + C[2 + j][reg] + bzv);
        float n_ = tanhf_(gnv + r_ * (C[4 + j][reg] + bnv));
        float hnew = (1.f - z_) * n_ + z_ * hold[j][reg];
        hold[j][reg] = valid ? hnew : hold[j][reg];
        float o = valid ? hnew : 0.f;
        if (reg == 0) ov.x = o; else if (reg == 1) ov.y = o; else if (reg == 2) ov.z = o; else ov.w = o;
        hv[reg] = (half_t)hold[j][reg];
      }
      if (m == 0) {
        *(half4v*)&hbuf[p ^ 1][u0 + j * 16] = hv;
        *(float4*)(outb + (size_t)t * (BB * HH) + u0 + j * 16) = ov;
      }
    }
    BARRIER_LDS();
  }
  if (m == 0) {
    #pragma unroll
    for (int j = 0; j < 2; ++j) {
      float4 hf;
      hf.x = hold[j][0]; hf.y = hold[j][1]; hf.z = hold[j][2]; hf.w = hold[j][3];
      *(float4*)(hT + (size_t)b * HH + u0 + j * 16) = hf;
    }
  }
}

// ---------------------------------------------------------------------------
// ctx[b, h*256+d] = sum_l wsoft[l,b,h] * out1[l,b,d]
// ---------------------------------------------------------------------------
__global__ void ctx_kernel(
    const float* __restrict__ wsoft, const float* __restrict__ out1,
    float* __restrict__ ctx)
{
  int b = blockIdx.x >> 3, h = blockIdx.x & 7;
  int d = threadIdx.x;  // 256
  float acc = 0.f;
  for (int l = 0; l < LL; ++l) {
    float w = wsoft[((size_t)l * BB + b) * NHH + h];
    acc += w * out1[((size_t)l * BB + b) * HH + d];
  }
  ctx[(size_t)b * (NHH * HH) + h * HH + d] = acc;
}

// ---------------------------------------------------------------------------
// final MLP: z = selu([ctx, hT] @ Wf0.T + bf0); logits = z @ Wf1.T + bf1;
// out = log_softmax(logits)
// ---------------------------------------------------------------------------
__global__ __launch_bounds__(512) void final_kernel(
    const float* __restrict__ ctx, const float* __restrict__ hT,
    const float* __restrict__ Wf0,   // [168][2304]
    const float* __restrict__ bf0,
    const float* __restrict__ Wf1,   // [100][168]
    const float* __restrict__ bf1,
    float* __restrict__ outp)        // [B][100]
{
  int b = blockIdx.x;
  int tid = threadIdx.x;
  int wave = tid >> 6, lane = tid & 63;
  __shared__ float4 xs4[CLSIN / 4];
  __shared__ float zs[F1];
  __shared__ float ls[ETA];
  float* xs = (float*)xs4;
  for (int i = tid; i < NHH * HH; i += 512) xs[i] = ctx[(size_t)b * (NHH * HH) + i];
  if (tid < HH) xs[NHH * HH + tid] = hT[(size_t)b * HH + tid];
  __syncthreads();
  for (int r = wave; r < F1; r += 8) {
    const float4* wp = (const float4*)(Wf0 + (size_t)r * CLSIN);
    float acc = 0.f;
    #pragma unroll
    for (int i = 0; i < CLSIN / 4 / 64; ++i) {  // 9
      float4 w = wp[lane + 64 * i];
      float4 x = xs4[lane + 64 * i];
      acc += w.x * x.x + w.y * x.y + w.z * x.z + w.w * x.w;
    }
    #pragma unroll
    for (int off = 32; off > 0; off >>= 1) acc += __shfl_xor(acc, off, 64);
    if (lane == 0) {
      float x = acc + bf0[r];
      const float alpha = 1.6732632423543772f, scale = 1.0507009873554805f;
      zs[r] = scale * (x > 0.f ? x : alpha * (__expf(x) - 1.f));
    }
  }
  __syncthreads();
  for (int r = wave; r < ETA; r += 8) {
    float acc = 0.f;
    for (int k = lane; k < F1; k += 64) acc += Wf1[r * F1 + k] * zs[k];
    #pragma unroll
    for (int off = 32; off > 0; off >>= 1) acc += __shfl_xor(acc, off, 64);
    if (lane == 0) ls[r] = acc + bf1[r];
  }
  __syncthreads();
  if (wave == 0) {
    float v0 = (lane < ETA) ? ls[lane] : -1e30f;
    float v1 = (lane + 64 < ETA) ? ls[lane + 64] : -1e30f;
    float m = fmaxf(v0, v1);
    #pragma unroll
    for (int off = 32; off > 0; off >>= 1) m = fmaxf(m, __shfl_xor(m, off, 64));
    float s = __expf(v0 - m) + __expf(v1 - m);
    #pragma unroll
    for (int off = 32; off > 0; off >>= 1) s += __shfl_xor(s, off, 64);
    float lse = m + __logf(s);
    if (lane < ETA) outp[(size_t)b * ETA + lane] = v0 - lse;
    if (lane + 64 < ETA) outp[(size_t)b * ETA + lane + 64] = v1 - lse;
  }
}

extern "C" void kernel_launch(void* const* d_in, const int* in_sizes, int n_in,
                              void* d_out, int out_size, void* d_ws, size_t ws_size,
                              hipStream_t stream) {
  const int*   node  = (const int*)d_in[0];
  const float* ts    = (const float*)d_in[1];
  const int*   slen  = (const int*)d_in[2];
  const float* table = (const float*)d_in[3];
  const float* Wih0  = (const float*)d_in[4];
  const float* Whh0  = (const float*)d_in[5];
  const float* bih0  = (const float*)d_in[6];
  const float* bhh0  = (const float*)d_in[7];
  const float* Wih1  = (const float*)d_in[8];
  const float* Whh1  = (const float*)d_in[9];
  const float* bih1  = (const float*)d_in[10];
  const float* bhh1  = (const float*)d_in[11];
  const float* Wa0   = (const float*)d_in[12];
  const float* ba0   = (const float*)d_in[13];
  const float* Wa1   = (const float*)d_in[14];
  const float* ba1   = (const float*)d_in[15];
  const float* Wf0   = (const float*)d_in[16];
  const float* bf0   = (const float*)d_in[17];
  const float* Wf1   = (const float*)d_in[18];
  const float* bf1   = (const float*)d_in[19];

  char* ws = (char*)d_ws;
  size_t off = 0;
  auto alloc = [&](size_t n) { void* p = (void*)(ws + off); off += (n + 255) & ~(size_t)255; return p; };

  half2v* e_h2 = (half2v*)alloc((size_t)LL * BB * 64 * 4);
  float* U     = (float*)alloc((size_t)LL * BB * EE * 4);
  float* V     = (float*)alloc((size_t)LL * BB * EE * 4);
  float* gi    = (float*)alloc((size_t)LL * BB * G3 * 4);   // reused for both layers
  float* out0  = (float*)alloc((size_t)LL * BB * HH * 4);
  float* out1  = (float*)alloc((size_t)LL * BB * HH * 4);
  float* hTb   = (float*)alloc((size_t)BB * HH * 4);
  float* wpre  = (float*)alloc((size_t)LL * BB * NHH * 4);
  float* wsoft = (float*)alloc((size_t)LL * BB * NHH * 4);
  float* ctxb  = (float*)alloc((size_t)BB * NHH * HH * 4);
  half_t* Wa0Ta = (half_t*)alloc((size_t)128 * 128 * 2);
  half_t* Wa0Tb = (half_t*)alloc((size_t)128 * 128 * 2);
  half2v* Wih0T2 = (half2v*)alloc((size_t)65 * 768 * 4);
  half2v* Wih1T2 = (half2v*)alloc((size_t)128 * 768 * 4);
  half_t* Whh0h = (half_t*)alloc((size_t)G3 * HH * 2);
  half_t* Whh1h = (half_t*)alloc((size_t)G3 * HH * 2);
  if (off > ws_size) return;  // workspace too small: fail visibly

  const int prep_total = 16384 + 16384 + 65 * 768 + 128 * 768 + 196608 + 196608;
  prep_kernel<<<(prep_total + 255) / 256, 256, 0, stream>>>(
      Wa0, Wih0, Wih1, Whh0, Whh1, Wa0Ta, Wa0Tb, Wih0T2, Wih1T2, Whh0h, Whh1h);
  embed_uv_kernel<<<LL * BB, 128, 0, stream>>>(node, table, Wa0Ta, Wa0Tb, ba0, e_h2, U, V);
  attn_w_kernel<<<(LL / 4) * BB, 128, 0, stream>>>(U, V, Wa1, ba1, wpre);
  attn_softmax_kernel<<<BB * NHH, 128, 0, stream>>>(wpre, slen, wsoft);
  gi0_kernel<<<LL * BB / 8, 256, 0, stream>>>(e_h2, ts, Wih0T2, bih0, gi);
  gru_scan_kernel<<<BB, 512, 0, stream>>>(Whh0h, bhh0, gi, slen, out0, hTb);
  gi1_kernel<<<LL * BB / 8, 256, 0, stream>>>(out0, Wih1T2, bih1, gi);
  gru_scan_kernel<<<BB, 512, 0, stream>>>(Whh1h, bhh1, gi, slen, out1, hTb);
  ctx_kernel<<<BB * NHH, 256, 0, stream>>>(wsoft, out1, ctxb);
  final_kernel<<<BB, 512, 0, stream>>>(ctxb, hTb, Wf0, bf0, Wf1, bf1, (float*)d_out);
}

// Round 6
// 707.642 us; speedup vs baseline: 1.7876x; 1.7876x over previous
//
#include <hip/hip_runtime.h>
#include <hip/hip_bf16.h>

#define LL 128
#define BB 32
#define EE 128
#define HH 256
#define NHH 8
#define G3 768   // 3*H
#define IN0 130
#define ETA 100
#define F1 168
#define CLSIN 2304  // 8*256 + 256

typedef _Float16 half_t;
typedef __attribute__((ext_vector_type(2))) _Float16 half2v;
typedef __attribute__((ext_vector_type(8))) _Float16 f16x8;
typedef __attribute__((ext_vector_type(4))) float f32x4;

#if defined(__has_builtin)
#if __has_builtin(__builtin_amdgcn_fdot2)
#define HAVE_FDOT2 1
#endif
#endif

__device__ __forceinline__ float fdot2f(half2v a, half2v b, float c) {
#ifdef HAVE_FDOT2
  return __builtin_amdgcn_fdot2(a, b, c, false);
#else
  return c + (float)a.x * (float)b.x + (float)a.y * (float)b.y;
#endif
}

// LDS-only barrier: skip the compiler's vmcnt(0) drain (no cross-thread
// global-memory dependencies at our barriers).
#define BARRIER_LDS() __asm__ volatile("s_waitcnt lgkmcnt(0)\n\ts_barrier" ::: "memory")

__device__ __forceinline__ float sigmoidf_(float x) { return 1.0f / (1.0f + __expf(-x)); }
__device__ __forceinline__ float tanhf_(float x) { return 1.0f - 2.0f / (__expf(2.0f * x) + 1.0f); }

// ---------------------------------------------------------------------------
// prep: weight repack fp32 -> f16 (weights ~N(0,0.05^2): f16 rel err 5e-4)
// ---------------------------------------------------------------------------
__global__ void prep_kernel(
    const float* __restrict__ Wa0, const float* __restrict__ Wih0,
    const float* __restrict__ Wih1, const float* __restrict__ Whh0,
    const float* __restrict__ Whh1,
    half_t* __restrict__ Wa0Ta, half_t* __restrict__ Wa0Tb,
    half2v* __restrict__ Wih0T2, half2v* __restrict__ Wih1T2,
    half_t* __restrict__ Whh0h, half_t* __restrict__ Whh1h)
{
  int idx = blockIdx.x * blockDim.x + threadIdx.x;
  const int n1 = 16384, n2 = 16384, n3 = 65 * 768, n4 = 128 * 768, n5 = 196608;
  if (idx < n1) {
    int d = idx >> 7, k = idx & 127;
    Wa0Ta[idx] = (half_t)Wa0[k * 256 + d];
  } else if ((idx -= n1) < n2) {
    int d = idx >> 7, k = idx & 127;
    Wa0Tb[idx] = (half_t)Wa0[k * 256 + 128 + d];
  } else if ((idx -= n2) < n3) {
    int d2 = idx / 768, r = idx % 768;
    half2v w; w.x = (half_t)Wih0[r * IN0 + 2 * d2]; w.y = (half_t)Wih0[r * IN0 + 2 * d2 + 1];
    Wih0T2[idx] = w;
  } else if ((idx -= n3) < n4) {
    int d2 = idx / 768, r = idx % 768;
    half2v w; w.x = (half_t)Wih1[r * HH + 2 * d2]; w.y = (half_t)Wih1[r * HH + 2 * d2 + 1];
    Wih1T2[idx] = w;
  } else if ((idx -= n4) < n5) {
    Whh0h[idx] = (half_t)Whh0[idx];
  } else if ((idx -= n5) < n5) {
    Whh1h[idx] = (half_t)Whh1[idx];
  }
}

// ---------------------------------------------------------------------------
// embed gather + U/V factors of the pairwise attention
// ---------------------------------------------------------------------------
__global__ void embed_uv_kernel(
    const int* __restrict__ node,             // [L*B]
    const float* __restrict__ table,          // [20001][128]
    const half_t* __restrict__ Wa0Ta,         // [128 d][128 k]
    const half_t* __restrict__ Wa0Tb,
    const float* __restrict__ ba0,            // [128]
    half2v* __restrict__ e_h2,                // [L*B][64]
    float* __restrict__ U,
    float* __restrict__ V)
{
  int lb = blockIdx.x;
  int k = threadIdx.x;  // 128
  __shared__ float es[EE];
  int n = node[lb];
  float ev = table[(size_t)n * EE + k];
  es[k] = ev;
  __syncthreads();
  if (k < 64) {
    half2v p; p.x = (half_t)es[2 * k]; p.y = (half_t)es[2 * k + 1];
    e_h2[(size_t)lb * 64 + k] = p;
  }
  float u = 0.f, v = ba0[k];
  #pragma unroll 8
  for (int d = 0; d < EE; ++d) {
    float x = es[d];
    u += (float)Wa0Ta[d * EE + k] * x;
    v += (float)Wa0Tb[d * EE + k] * x;
  }
  U[(size_t)lb * EE + k] = u;
  V[(size_t)lb * EE + k] = v;
}

// ---------------------------------------------------------------------------
// w_pre[i,b,h] = sum_j sum_k Wa1[h,k] * relu(U[j,b,k]+V[i,b,k]) + L*ba1[h]
// ---------------------------------------------------------------------------
__global__ __launch_bounds__(128) void attn_w_kernel(
    const float* __restrict__ U, const float* __restrict__ V,
    const float* __restrict__ Wa1,  // [8][128]
    const float* __restrict__ ba1,  // [8]
    float* __restrict__ wpre)       // [L][B][8]
{
  int ig = blockIdx.x >> 5;
  int b = blockIdx.x & 31;
  int i0 = ig * 4;
  int k = threadIdx.x;  // 128
  float vk[4];
  #pragma unroll
  for (int ii = 0; ii < 4; ++ii) vk[ii] = V[((size_t)(i0 + ii) * BB + b) * EE + k];
  float wa[NHH], acc[4][NHH];
  #pragma unroll
  for (int h = 0; h < NHH; ++h) wa[h] = Wa1[h * EE + k];
  #pragma unroll
  for (int ii = 0; ii < 4; ++ii)
    #pragma unroll
    for (int h = 0; h < NHH; ++h) acc[ii][h] = 0.f;
  for (int j = 0; j < LL; ++j) {
    float u = U[((size_t)j * BB + b) * EE + k];
    #pragma unroll
    for (int ii = 0; ii < 4; ++ii) {
      float tv = fmaxf(u + vk[ii], 0.f);
      #pragma unroll
      for (int h = 0; h < NHH; ++h) acc[ii][h] += wa[h] * tv;
    }
  }
  __shared__ float part[2][32];
  int wave = k >> 6, lane = k & 63;
  #pragma unroll
  for (int ii = 0; ii < 4; ++ii)
    #pragma unroll
    for (int h = 0; h < NHH; ++h) {
      float a = acc[ii][h];
      #pragma unroll
      for (int off = 32; off > 0; off >>= 1) a += __shfl_xor(a, off, 64);
      if (lane == 0) part[wave][ii * 8 + h] = a;
    }
  __syncthreads();
  if (k < 32) {
    int ii = k >> 3, h = k & 7;
    float w = part[0][k] + part[1][k] + (float)LL * ba1[h];
    wpre[((size_t)(i0 + ii) * BB + b) * NHH + h] = w;
  }
}

// softmax over l of (w * mask): masked entries become 0 and STAY in the softmax
__global__ void attn_softmax_kernel(
    const float* __restrict__ wpre, const int* __restrict__ slen,
    float* __restrict__ wsoft)
{
  int b = blockIdx.x >> 3;
  int h = blockIdx.x & 7;
  int l = threadIdx.x;  // 128
  int len = slen[b];
  float x = wpre[((size_t)l * BB + b) * NHH + h];
  float xv = (l < len) ? x : 0.f;
  float m = xv;
  #pragma unroll
  for (int off = 32; off > 0; off >>= 1) m = fmaxf(m, __shfl_xor(m, off, 64));
  __shared__ float sm[2], ss[2];
  int wave = l >> 6;
  if ((l & 63) == 0) sm[wave] = m;
  __syncthreads();
  m = fmaxf(sm[0], sm[1]);
  float e = __expf(xv - m);
  float s = e;
  #pragma unroll
  for (int off = 32; off > 0; off >>= 1) s += __shfl_xor(s, off, 64);
  if ((l & 63) == 0) ss[wave] = s;
  __syncthreads();
  s = ss[0] + ss[1];
  wsoft[((size_t)l * BB + b) * NHH + h] = e / s;
}

// ---------------------------------------------------------------------------
// gi0: [e, ts] @ Wih0.T + bih0 (+ bhh0 for r,z gates), 8 lb per block
// ---------------------------------------------------------------------------
__global__ __launch_bounds__(256) void gi0_kernel(
    const half2v* __restrict__ e_h2, const float* __restrict__ ts,
    const half2v* __restrict__ W2,   // [65][768]
    const float* __restrict__ bih,
    const float* __restrict__ bhh,   // folded for r,z (NOT n: bhn sits inside r*(...))
    float* __restrict__ gi)
{
  int lb0 = blockIdx.x * 8;
  int tid = threadIdx.x;  // 256
  __shared__ half2v xs2[8][66];
  for (int idx = tid; idx < 512; idx += 256) {
    int q = idx >> 6, d2 = idx & 63;
    xs2[q][d2] = e_h2[(size_t)(lb0 + q) * 64 + d2];
  }
  if (tid < 8) {
    half2v t2; t2.x = (half_t)ts[(lb0 + tid) * 2]; t2.y = (half_t)ts[(lb0 + tid) * 2 + 1];
    xs2[tid][64] = t2;
  }
  __syncthreads();
  float acc[8][3];
  #pragma unroll
  for (int q = 0; q < 8; ++q) { acc[q][0] = 0.f; acc[q][1] = 0.f; acc[q][2] = 0.f; }
  for (int d2 = 0; d2 < 65; ++d2) {
    half2v w0 = W2[d2 * 768 + tid];
    half2v w1 = W2[d2 * 768 + 256 + tid];
    half2v w2 = W2[d2 * 768 + 512 + tid];
    #pragma unroll
    for (int q = 0; q < 8; ++q) {
      half2v x = xs2[q][d2];
      acc[q][0] = fdot2f(w0, x, acc[q][0]);
      acc[q][1] = fdot2f(w1, x, acc[q][1]);
      acc[q][2] = fdot2f(w2, x, acc[q][2]);
    }
  }
  float b0 = bih[tid] + bhh[tid];
  float b1 = bih[256 + tid] + bhh[256 + tid];
  float b2 = bih[512 + tid];
  #pragma unroll
  for (int q = 0; q < 8; ++q) {
    float* gp = gi + (size_t)(lb0 + q) * G3;
    gp[tid] = acc[q][0] + b0; gp[256 + tid] = acc[q][1] + b1; gp[512 + tid] = acc[q][2] + b2;
  }
}

// ---------------------------------------------------------------------------
// gi1: out0 @ Wih1.T + bih1 (+ bhh1 for r,z gates), 8 lb per block
// ---------------------------------------------------------------------------
__global__ __launch_bounds__(256) void gi1_kernel(
    const float* __restrict__ out0,  // [L*B][256]
    const half2v* __restrict__ W2,   // [128][768]
    const float* __restrict__ bih,
    const float* __restrict__ bhh,
    float* __restrict__ gi)
{
  int lb0 = blockIdx.x * 8;
  int tid = threadIdx.x;  // 256
  __shared__ half2v xs2[8][128];
  for (int idx = tid; idx < 1024; idx += 256) {
    int q = idx >> 7, d2 = idx & 127;
    float2 v = ((const float2*)(out0 + (size_t)(lb0 + q) * HH))[d2];
    half2v x; x.x = (half_t)v.x; x.y = (half_t)v.y;
    xs2[q][d2] = x;
  }
  __syncthreads();
  float acc[8][3];
  #pragma unroll
  for (int q = 0; q < 8; ++q) { acc[q][0] = 0.f; acc[q][1] = 0.f; acc[q][2] = 0.f; }
  for (int d2 = 0; d2 < 128; ++d2) {
    half2v w0 = W2[d2 * 768 + tid];
    half2v w1 = W2[d2 * 768 + 256 + tid];
    half2v w2 = W2[d2 * 768 + 512 + tid];
    #pragma unroll
    for (int q = 0; q < 8; ++q) {
      half2v x = xs2[q][d2];
      acc[q][0] = fdot2f(w0, x, acc[q][0]);
      acc[q][1] = fdot2f(w1, x, acc[q][1]);
      acc[q][2] = fdot2f(w2, x, acc[q][2]);
    }
  }
  float b0 = bih[tid] + bhh[tid];
  float b1 = bih[256 + tid] + bhh[256 + tid];
  float b2 = bih[512 + tid];
  #pragma unroll
  for (int q = 0; q < 8; ++q) {
    float* gp = gi + (size_t)(lb0 + q) * G3;
    gp[tid] = acc[q][0] + b0; gp[256 + tid] = acc[q][1] + b1; gp[512 + tid] = acc[q][2] + b2;
  }
}

// ---------------------------------------------------------------------------
// GRU scan v6 (MFMA, 256 threads, 1 wave/SIMD): one block per batch.
//
// HARD CONSTRAINT learned R3-R5: a 512-thread block forces 2 waves/SIMD ->
// <=256 unified regs/wave, which can NEVER hold A(192)+working set (R4's
// latency, R5's spill). A 256-thread block gets the full 512-reg unified
// budget: wave w holds ALL of its Whh slab in registers.
//
// Wave w owns all 3 gates of units w*64..w*64+63: 12 tiles (g=0..2, j=0..3),
// tile row = g*256 + w*64 + j*16 + m. A = 96 f16x8 frags = 384 regs
// (AGPR-resident; MFMA reads AGPR natively - R4-verified correct).
// B = h broadcast by (kg,e), same k-convention as A (verified R4/R5).
// Working set kept scalar-lean via the gsum-LDS tail: g0..g2 = 3 regs,
// hold = 1 reg; bhr/bhz folded into gi upstream (bhn kept: it sits inside
// r*(...)). Total ~490 <= 512. bf[8] prefetched (one lgkm wait);
// g-loads issued at step top ("memory" clobber on barriers keeps them
// hoisted) so their latency hides under the 96-MFMA block.
// ---------------------------------------------------------------------------
__global__ __launch_bounds__(256, 1) void gru_scan_kernel(
    const half_t* __restrict__ Whhh,         // [768][256] f16
    const float* __restrict__ bhh,           // [768]
    const float* __restrict__ gi,            // [L][B][768] (r,z biases folded)
    const int* __restrict__ slen,            // [B]
    float* __restrict__ out,                 // [L][B][256]
    float* __restrict__ hT)                  // [B][256]
{
  const int b = blockIdx.x;
  const int tid = threadIdx.x;  // 256
  const int w = tid >> 6;       // wave 0..3
  const int lane = tid & 63;
  const int m = lane & 15;      // A row-in-tile / D col
  const int kg = lane >> 4;     // k-group 0..3

  __shared__ __align__(16) half_t hbuf[2][HH];
  __shared__ __align__(16) float gsum[G3];

  // A-fragments: 96 x f16x8 = 384 unified regs
  f16x8 A[96];
  #pragma unroll
  for (int g = 0; g < 3; ++g)
    #pragma unroll
    for (int j = 0; j < 4; ++j) {
      int row = (g << 8) + (w << 6) + (j << 4) + m;
      const half_t* wb = Whhh + (size_t)row * HH + kg * 8;
      #pragma unroll
      for (int kc = 0; kc < 8; ++kc)
        A[(g * 4 + j) * 8 + kc] = *(const f16x8*)(wb + kc * 32);
    }

  const int len = slen[b];
  const float bhn = bhh[2 * HH + tid];
  float hold = 0.f;
  hbuf[0][tid] = (half_t)0.f;
  hbuf[1][tid] = (half_t)0.f;
  __syncthreads();

  const float* gib = gi + (size_t)b * G3;
  float* outb = out + (size_t)b * HH;

  #pragma unroll 1
  for (int t = 0; t < LL; ++t) {
    const int p = t & 1;
    // gate inputs — issue first, consumed in the tail (latency hidden)
    const float* gp = gib + (size_t)t * (BB * G3);
    float g0 = gp[tid], g1 = gp[HH + tid], g2 = gp[2 * HH + tid];
    // all 8 B-fragments up front: back-to-back ds_read_b128, one wait
    f16x8 bf[8];
    #pragma unroll
    for (int kc = 0; kc < 8; ++kc)
      bf[kc] = *(const f16x8*)&hbuf[p][kc * 32 + kg * 8];
    f32x4 C[12];
    #pragma unroll
    for (int tl = 0; tl < 12; ++tl) C[tl] = (f32x4){0.f, 0.f, 0.f, 0.f};
    #pragma unroll
    for (int kc = 0; kc < 8; ++kc)
      #pragma unroll
      for (int tl = 0; tl < 12; ++tl)
        C[tl] = __builtin_amdgcn_mfma_f32_16x16x32_f16(A[tl * 8 + kc], bf[kc], C[tl], 0, 0, 0);
    // D layout (HW-verified): col=lane&15, row=kg*4+reg. Columns identical
    // (B broadcast) -> m==0 lanes store gate sums for units w*64+j*16+kg*4+reg.
    if (m == 0) {
      #pragma unroll
      for (int g = 0; g < 3; ++g)
        #pragma unroll
        for (int j = 0; j < 4; ++j)
          *(f32x4*)&gsum[(g << 8) + (w << 6) + (j << 4) + (kg << 2)] = C[g * 4 + j];
    }
    BARRIER_LDS();
    {
      float r_ = sigmoidf_(g0 + gsum[tid]);
      float z_ = sigmoidf_(g1 + gsum[HH + tid]);
      float n_ = tanhf_(g2 + r_ * (gsum[2 * HH + tid] + bhn));
      float hnew = (1.f - z_) * n_ + z_ * hold;
      bool valid = t < len;
      hold = valid ? hnew : hold;
      hbuf[p ^ 1][tid] = (half_t)hold;
      outb[(size_t)t * (BB * HH) + tid] = valid ? hnew : 0.f;
    }
    BARRIER_LDS();
  }
  hT[(size_t)b * HH + tid] = hold;
}

// ---------------------------------------------------------------------------
// ctx[b, h*256+d] = sum_l wsoft[l,b,h] * out1[l,b,d]
// ---------------------------------------------------------------------------
__global__ void ctx_kernel(
    const float* __restrict__ wsoft, const float* __restrict__ out1,
    float* __restrict__ ctx)
{
  int b = blockIdx.x >> 3, h = blockIdx.x & 7;
  int d = threadIdx.x;  // 256
  float acc = 0.f;
  for (int l = 0; l < LL; ++l) {
    float w = wsoft[((size_t)l * BB + b) * NHH + h];
    acc += w * out1[((size_t)l * BB + b) * HH + d];
  }
  ctx[(size_t)b * (NHH * HH) + h * HH + d] = acc;
}

// ---------------------------------------------------------------------------
// final MLP: z = selu([ctx, hT] @ Wf0.T + bf0); logits = z @ Wf1.T + bf1;
// out = log_softmax(logits)
// ---------------------------------------------------------------------------
__global__ __launch_bounds__(512) void final_kernel(
    const float* __restrict__ ctx, const float* __restrict__ hT,
    const float* __restrict__ Wf0,   // [168][2304]
    const float* __restrict__ bf0,
    const float* __restrict__ Wf1,   // [100][168]
    const float* __restrict__ bf1,
    float* __restrict__ outp)        // [B][100]
{
  int b = blockIdx.x;
  int tid = threadIdx.x;
  int wave = tid >> 6, lane = tid & 63;
  __shared__ float4 xs4[CLSIN / 4];
  __shared__ float zs[F1];
  __shared__ float ls[ETA];
  float* xs = (float*)xs4;
  for (int i = tid; i < NHH * HH; i += 512) xs[i] = ctx[(size_t)b * (NHH * HH) + i];
  if (tid < HH) xs[NHH * HH + tid] = hT[(size_t)b * HH + tid];
  __syncthreads();
  for (int r = wave; r < F1; r += 8) {
    const float4* wp = (const float4*)(Wf0 + (size_t)r * CLSIN);
    float acc = 0.f;
    #pragma unroll
    for (int i = 0; i < CLSIN / 4 / 64; ++i) {  // 9
      float4 w = wp[lane + 64 * i];
      float4 x = xs4[lane + 64 * i];
      acc += w.x * x.x + w.y * x.y + w.z * x.z + w.w * x.w;
    }
    #pragma unroll
    for (int off = 32; off > 0; off >>= 1) acc += __shfl_xor(acc, off, 64);
    if (lane == 0) {
      float x = acc + bf0[r];
      const float alpha = 1.6732632423543772f, scale = 1.0507009873554805f;
      zs[r] = scale * (x > 0.f ? x : alpha * (__expf(x) - 1.f));
    }
  }
  __syncthreads();
  for (int r = wave; r < ETA; r += 8) {
    float acc = 0.f;
    for (int k = lane; k < F1; k += 64) acc += Wf1[r * F1 + k] * zs[k];
    #pragma unroll
    for (int off = 32; off > 0; off >>= 1) acc += __shfl_xor(acc, off, 64);
    if (lane == 0) ls[r] = acc + bf1[r];
  }
  __syncthreads();
  if (wave == 0) {
    float v0 = (lane < ETA) ? ls[lane] : -1e30f;
    float v1 = (lane + 64 < ETA) ? ls[lane + 64] : -1e30f;
    float m = fmaxf(v0, v1);
    #pragma unroll
    for (int off = 32; off > 0; off >>= 1) m = fmaxf(m, __shfl_xor(m, off, 64));
    float s = __expf(v0 - m) + __expf(v1 - m);
    #pragma unroll
    for (int off = 32; off > 0; off >>= 1) s += __shfl_xor(s, off, 64);
    float lse = m + __logf(s);
    if (lane < ETA) outp[(size_t)b * ETA + lane] = v0 - lse;
    if (lane + 64 < ETA) outp[(size_t)b * ETA + lane + 64] = v1 - lse;
  }
}

extern "C" void kernel_launch(void* const* d_in, const int* in_sizes, int n_in,
                              void* d_out, int out_size, void* d_ws, size_t ws_size,
                              hipStream_t stream) {
  const int*   node  = (const int*)d_in[0];
  const float* ts    = (const float*)d_in[1];
  const int*   slen  = (const int*)d_in[2];
  const float* table = (const float*)d_in[3];
  const float* Wih0  = (const float*)d_in[4];
  const float* Whh0  = (const float*)d_in[5];
  const float* bih0  = (const float*)d_in[6];
  const float* bhh0  = (const float*)d_in[7];
  const float* Wih1  = (const float*)d_in[8];
  const float* Whh1  = (const float*)d_in[9];
  const float* bih1  = (const float*)d_in[10];
  const float* bhh1  = (const float*)d_in[11];
  const float* Wa0   = (const float*)d_in[12];
  const float* ba0   = (const float*)d_in[13];
  const float* Wa1   = (const float*)d_in[14];
  const float* ba1   = (const float*)d_in[15];
  const float* Wf0   = (const float*)d_in[16];
  const float* bf0   = (const float*)d_in[17];
  const float* Wf1   = (const float*)d_in[18];
  const float* bf1   = (const float*)d_in[19];

  char* ws = (char*)d_ws;
  size_t off = 0;
  auto alloc = [&](size_t n) { void* p = (void*)(ws + off); off += (n + 255) & ~(size_t)255; return p; };

  half2v* e_h2 = (half2v*)alloc((size_t)LL * BB * 64 * 4);
  float* U     = (float*)alloc((size_t)LL * BB * EE * 4);
  float* V     = (float*)alloc((size_t)LL * BB * EE * 4);
  float* gi    = (float*)alloc((size_t)LL * BB * G3 * 4);   // reused for both layers
  float* out0  = (float*)alloc((size_t)LL * BB * HH * 4);
  float* out1  = (float*)alloc((size_t)LL * BB * HH * 4);
  float* hTb   = (float*)alloc((size_t)BB * HH * 4);
  float* wpre  = (float*)alloc((size_t)LL * BB * NHH * 4);
  float* wsoft = (float*)alloc((size_t)LL * BB * NHH * 4);
  float* ctxb  = (float*)alloc((size_t)BB * NHH * HH * 4);
  half_t* Wa0Ta = (half_t*)alloc((size_t)128 * 128 * 2);
  half_t* Wa0Tb = (half_t*)alloc((size_t)128 * 128 * 2);
  half2v* Wih0T2 = (half2v*)alloc((size_t)65 * 768 * 4);
  half2v* Wih1T2 = (half2v*)alloc((size_t)128 * 768 * 4);
  half_t* Whh0h = (half_t*)alloc((size_t)G3 * HH * 2);
  half_t* Whh1h = (half_t*)alloc((size_t)G3 * HH * 2);
  if (off > ws_size) return;  // workspace too small: fail visibly

  const int prep_total = 16384 + 16384 + 65 * 768 + 128 * 768 + 196608 + 196608;
  prep_kernel<<<(prep_total + 255) / 256, 256, 0, stream>>>(
      Wa0, Wih0, Wih1, Whh0, Whh1, Wa0Ta, Wa0Tb, Wih0T2, Wih1T2, Whh0h, Whh1h);
  embed_uv_kernel<<<LL * BB, 128, 0, stream>>>(node, table, Wa0Ta, Wa0Tb, ba0, e_h2, U, V);
  attn_w_kernel<<<(LL / 4) * BB, 128, 0, stream>>>(U, V, Wa1, ba1, wpre);
  attn_softmax_kernel<<<BB * NHH, 128, 0, stream>>>(wpre, slen, wsoft);
  gi0_kernel<<<LL * BB / 8, 256, 0, stream>>>(e_h2, ts, Wih0T2, bih0, bhh0, gi);
  gru_scan_kernel<<<BB, 256, 0, stream>>>(Whh0h, bhh0, gi, slen, out0, hTb);
  gi1_kernel<<<LL * BB / 8, 256, 0, stream>>>(out0, Wih1T2, bih1, bhh1, gi);
  gru_scan_kernel<<<BB, 256, 0, stream>>>(Whh1h, bhh1, gi, slen, out1, hTb);
  ctx_kernel<<<BB * NHH, 256, 0, stream>>>(wsoft, out1, ctxb);
  final_kernel<<<BB, 512, 0, stream>>>(ctxb, hTb, Wf0, bf0, Wf1, bf1, (float*)d_out);
}

// Round 7
// 624.617 us; speedup vs baseline: 2.0252x; 1.1329x over previous
//
#include <hip/hip_runtime.h>
#include <hip/hip_bf16.h>

#define LL 128
#define BB 32
#define EE 128
#define HH 256
#define NHH 8
#define G3 768   // 3*H
#define IN0 130
#define ETA 100
#define F1 168
#define CLSIN 2304  // 8*256 + 256

typedef _Float16 half_t;
typedef __attribute__((ext_vector_type(2))) _Float16 half2v;
typedef __attribute__((ext_vector_type(16))) unsigned int uint16v;

#if defined(__has_builtin)
#if __has_builtin(__builtin_amdgcn_fdot2)
#define HAVE_FDOT2 1
#endif
#endif

__device__ __forceinline__ float fdot2f(half2v a, half2v b, float c) {
#ifdef HAVE_FDOT2
  return __builtin_amdgcn_fdot2(a, b, c, false);
#else
  return c + (float)a.x * (float)b.x + (float)a.y * (float)b.y;
#endif
}
__device__ __forceinline__ float fdot2u(unsigned int a, unsigned int b, float c) {
  return fdot2f(__builtin_bit_cast(half2v, a), __builtin_bit_cast(half2v, b), c);
}

// LDS-only barrier: skip the compiler's vmcnt(0) drain (no cross-thread
// global-memory dependencies at our barriers).
#define BARRIER_LDS() __asm__ volatile("s_waitcnt lgkmcnt(0)\n\ts_barrier" ::: "memory")

__device__ __forceinline__ float sigmoidf_(float x) { return 1.0f / (1.0f + __expf(-x)); }
__device__ __forceinline__ float tanhf_(float x) { return 1.0f - 2.0f / (__expf(2.0f * x) + 1.0f); }

// ---------------------------------------------------------------------------
// prep: weight repack fp32 -> f16 (weights ~N(0,0.05^2): f16 rel err 5e-4)
// ---------------------------------------------------------------------------
__global__ void prep_kernel(
    const float* __restrict__ Wa0, const float* __restrict__ Wih0,
    const float* __restrict__ Wih1, const float* __restrict__ Whh0,
    const float* __restrict__ Whh1,
    half_t* __restrict__ Wa0Ta, half_t* __restrict__ Wa0Tb,
    half2v* __restrict__ Wih0T2, half2v* __restrict__ Wih1T2,
    half_t* __restrict__ Whh0h, half_t* __restrict__ Whh1h)
{
  int idx = blockIdx.x * blockDim.x + threadIdx.x;
  const int n1 = 16384, n2 = 16384, n3 = 65 * 768, n4 = 128 * 768, n5 = 196608;
  if (idx < n1) {
    int d = idx >> 7, k = idx & 127;
    Wa0Ta[idx] = (half_t)Wa0[k * 256 + d];
  } else if ((idx -= n1) < n2) {
    int d = idx >> 7, k = idx & 127;
    Wa0Tb[idx] = (half_t)Wa0[k * 256 + 128 + d];
  } else if ((idx -= n2) < n3) {
    int d2 = idx / 768, r = idx % 768;
    half2v w; w.x = (half_t)Wih0[r * IN0 + 2 * d2]; w.y = (half_t)Wih0[r * IN0 + 2 * d2 + 1];
    Wih0T2[idx] = w;
  } else if ((idx -= n3) < n4) {
    int d2 = idx / 768, r = idx % 768;
    half2v w; w.x = (half_t)Wih1[r * HH + 2 * d2]; w.y = (half_t)Wih1[r * HH + 2 * d2 + 1];
    Wih1T2[idx] = w;
  } else if ((idx -= n4) < n5) {
    Whh0h[idx] = (half_t)Whh0[idx];
  } else if ((idx -= n5) < n5) {
    Whh1h[idx] = (half_t)Whh1[idx];
  }
}

// ---------------------------------------------------------------------------
// embed gather + U/V factors of the pairwise attention
// ---------------------------------------------------------------------------
__global__ void embed_uv_kernel(
    const int* __restrict__ node,             // [L*B]
    const float* __restrict__ table,          // [20001][128]
    const half_t* __restrict__ Wa0Ta,         // [128 d][128 k]
    const half_t* __restrict__ Wa0Tb,
    const float* __restrict__ ba0,            // [128]
    half2v* __restrict__ e_h2,                // [L*B][64]
    float* __restrict__ U,
    float* __restrict__ V)
{
  int lb = blockIdx.x;
  int k = threadIdx.x;  // 128
  __shared__ float es[EE];
  int n = node[lb];
  float ev = table[(size_t)n * EE + k];
  es[k] = ev;
  __syncthreads();
  if (k < 64) {
    half2v p; p.x = (half_t)es[2 * k]; p.y = (half_t)es[2 * k + 1];
    e_h2[(size_t)lb * 64 + k] = p;
  }
  float u = 0.f, v = ba0[k];
  #pragma unroll 8
  for (int d = 0; d < EE; ++d) {
    float x = es[d];
    u += (float)Wa0Ta[d * EE + k] * x;
    v += (float)Wa0Tb[d * EE + k] * x;
  }
  U[(size_t)lb * EE + k] = u;
  V[(size_t)lb * EE + k] = v;
}

// ---------------------------------------------------------------------------
// w_pre[i,b,h] = sum_j sum_k Wa1[h,k] * relu(U[j,b,k]+V[i,b,k]) + L*ba1[h]
// ---------------------------------------------------------------------------
__global__ __launch_bounds__(128) void attn_w_kernel(
    const float* __restrict__ U, const float* __restrict__ V,
    const float* __restrict__ Wa1,  // [8][128]
    const float* __restrict__ ba1,  // [8]
    float* __restrict__ wpre)       // [L][B][8]
{
  int ig = blockIdx.x >> 5;
  int b = blockIdx.x & 31;
  int i0 = ig * 4;
  int k = threadIdx.x;  // 128
  float vk[4];
  #pragma unroll
  for (int ii = 0; ii < 4; ++ii) vk[ii] = V[((size_t)(i0 + ii) * BB + b) * EE + k];
  float wa[NHH], acc[4][NHH];
  #pragma unroll
  for (int h = 0; h < NHH; ++h) wa[h] = Wa1[h * EE + k];
  #pragma unroll
  for (int ii = 0; ii < 4; ++ii)
    #pragma unroll
    for (int h = 0; h < NHH; ++h) acc[ii][h] = 0.f;
  for (int j = 0; j < LL; ++j) {
    float u = U[((size_t)j * BB + b) * EE + k];
    #pragma unroll
    for (int ii = 0; ii < 4; ++ii) {
      float tv = fmaxf(u + vk[ii], 0.f);
      #pragma unroll
      for (int h = 0; h < NHH; ++h) acc[ii][h] += wa[h] * tv;
    }
  }
  __shared__ float part[2][32];
  int wave = k >> 6, lane = k & 63;
  #pragma unroll
  for (int ii = 0; ii < 4; ++ii)
    #pragma unroll
    for (int h = 0; h < NHH; ++h) {
      float a = acc[ii][h];
      #pragma unroll
      for (int off = 32; off > 0; off >>= 1) a += __shfl_xor(a, off, 64);
      if (lane == 0) part[wave][ii * 8 + h] = a;
    }
  __syncthreads();
  if (k < 32) {
    int ii = k >> 3, h = k & 7;
    float w = part[0][k] + part[1][k] + (float)LL * ba1[h];
    wpre[((size_t)(i0 + ii) * BB + b) * NHH + h] = w;
  }
}

// softmax over l of (w * mask): masked entries become 0 and STAY in the softmax
__global__ void attn_softmax_kernel(
    const float* __restrict__ wpre, const int* __restrict__ slen,
    float* __restrict__ wsoft)
{
  int b = blockIdx.x >> 3;
  int h = blockIdx.x & 7;
  int l = threadIdx.x;  // 128
  int len = slen[b];
  float x = wpre[((size_t)l * BB + b) * NHH + h];
  float xv = (l < len) ? x : 0.f;
  float m = xv;
  #pragma unroll
  for (int off = 32; off > 0; off >>= 1) m = fmaxf(m, __shfl_xor(m, off, 64));
  __shared__ float sm[2], ss[2];
  int wave = l >> 6;
  if ((l & 63) == 0) sm[wave] = m;
  __syncthreads();
  m = fmaxf(sm[0], sm[1]);
  float e = __expf(xv - m);
  float s = e;
  #pragma unroll
  for (int off = 32; off > 0; off >>= 1) s += __shfl_xor(s, off, 64);
  if ((l & 63) == 0) ss[wave] = s;
  __syncthreads();
  s = ss[0] + ss[1];
  wsoft[((size_t)l * BB + b) * NHH + h] = e / s;
}

// ---------------------------------------------------------------------------
// gi0: [e, ts] @ Wih0.T + bih0 (+ bhh0 for r,z gates), 8 lb per block
// ---------------------------------------------------------------------------
__global__ __launch_bounds__(256) void gi0_kernel(
    const half2v* __restrict__ e_h2, const float* __restrict__ ts,
    const half2v* __restrict__ W2,   // [65][768]
    const float* __restrict__ bih,
    const float* __restrict__ bhh,   // folded for r,z (NOT n: bhn sits inside r*(...))
    float* __restrict__ gi)
{
  int lb0 = blockIdx.x * 8;
  int tid = threadIdx.x;  // 256
  __shared__ half2v xs2[8][66];
  for (int idx = tid; idx < 512; idx += 256) {
    int q = idx >> 6, d2 = idx & 63;
    xs2[q][d2] = e_h2[(size_t)(lb0 + q) * 64 + d2];
  }
  if (tid < 8) {
    half2v t2; t2.x = (half_t)ts[(lb0 + tid) * 2]; t2.y = (half_t)ts[(lb0 + tid) * 2 + 1];
    xs2[tid][64] = t2;
  }
  __syncthreads();
  float acc[8][3];
  #pragma unroll
  for (int q = 0; q < 8; ++q) { acc[q][0] = 0.f; acc[q][1] = 0.f; acc[q][2] = 0.f; }
  for (int d2 = 0; d2 < 65; ++d2) {
    half2v w0 = W2[d2 * 768 + tid];
    half2v w1 = W2[d2 * 768 + 256 + tid];
    half2v w2 = W2[d2 * 768 + 512 + tid];
    #pragma unroll
    for (int q = 0; q < 8; ++q) {
      half2v x = xs2[q][d2];
      acc[q][0] = fdot2f(w0, x, acc[q][0]);
      acc[q][1] = fdot2f(w1, x, acc[q][1]);
      acc[q][2] = fdot2f(w2, x, acc[q][2]);
    }
  }
  float b0 = bih[tid] + bhh[tid];
  float b1 = bih[256 + tid] + bhh[256 + tid];
  float b2 = bih[512 + tid];
  #pragma unroll
  for (int q = 0; q < 8; ++q) {
    float* gp = gi + (size_t)(lb0 + q) * G3;
    gp[tid] = acc[q][0] + b0; gp[256 + tid] = acc[q][1] + b1; gp[512 + tid] = acc[q][2] + b2;
  }
}

// ---------------------------------------------------------------------------
// gi1: out0 @ Wih1.T + bih1 (+ bhh1 for r,z gates), 8 lb per block
// ---------------------------------------------------------------------------
__global__ __launch_bounds__(256) void gi1_kernel(
    const float* __restrict__ out0,  // [L*B][256]
    const half2v* __restrict__ W2,   // [128][768]
    const float* __restrict__ bih,
    const float* __restrict__ bhh,
    float* __restrict__ gi)
{
  int lb0 = blockIdx.x * 8;
  int tid = threadIdx.x;  // 256
  __shared__ half2v xs2[8][128];
  for (int idx = tid; idx < 1024; idx += 256) {
    int q = idx >> 7, d2 = idx & 127;
    float2 v = ((const float2*)(out0 + (size_t)(lb0 + q) * HH))[d2];
    half2v x; x.x = (half_t)v.x; x.y = (half_t)v.y;
    xs2[q][d2] = x;
  }
  __syncthreads();
  float acc[8][3];
  #pragma unroll
  for (int q = 0; q < 8; ++q) { acc[q][0] = 0.f; acc[q][1] = 0.f; acc[q][2] = 0.f; }
  for (int d2 = 0; d2 < 128; ++d2) {
    half2v w0 = W2[d2 * 768 + tid];
    half2v w1 = W2[d2 * 768 + 256 + tid];
    half2v w2 = W2[d2 * 768 + 512 + tid];
    #pragma unroll
    for (int q = 0; q < 8; ++q) {
      half2v x = xs2[q][d2];
      acc[q][0] = fdot2f(w0, x, acc[q][0]);
      acc[q][1] = fdot2f(w1, x, acc[q][1]);
      acc[q][2] = fdot2f(w2, x, acc[q][2]);
    }
  }
  float b0 = bih[tid] + bhh[tid];
  float b1 = bih[256 + tid] + bhh[256 + tid];
  float b2 = bih[512 + tid];
  #pragma unroll
  for (int q = 0; q < 8; ++q) {
    float* gp = gi + (size_t)(lb0 + q) * G3;
    gp[tid] = acc[q][0] + b0; gp[256 + tid] = acc[q][1] + b1; gp[512 + tid] = acc[q][2] + b2;
  }
}

// ---------------------------------------------------------------------------
// GRU scan v7 (row-per-thread VALU): one block per batch, 768 threads.
//
// Register invariant: W-regs/thread = 98304 pairs / threads. At 768 threads
// each thread owns ONE full row of Whh = 128 uint pairs = 8 x uint16v.
// 12 waves = 3 waves/SIMD -> ~170-reg budget; 128 W + ~30 working = ~158 ✓
// (first geometry where W fits ARCH VGPRs with slack — R0/R2's 512-thread
// blocks cap at 256 and forced AGPR shuttling; R3/R5 spilled).
// No cross-lane reduce: thread's dot product is complete -> one gsum[tid]
// store. h reads are same-address wave BROADCASTS (conflict-free by
// construction). dot2 issue/SIMD = 3 waves x 128 x 2cyc = 768 (the floor).
// Two accumulators break the dep chain. No asm pins (never helped).
// ---------------------------------------------------------------------------
__global__ __launch_bounds__(768, 3) void gru_scan_kernel(
    const half_t* __restrict__ Whhh,         // [768][256] f16
    const float* __restrict__ bhh,           // [768]
    const float* __restrict__ gi,            // [L][B][768] (r,z biases folded)
    const int* __restrict__ slen,            // [B]
    float* __restrict__ out,                 // [L][B][256]
    float* __restrict__ hT)                  // [B][256]
{
  const int b = blockIdx.x;
  const int tid = threadIdx.x;  // row index 0..767
  __shared__ __align__(16) half_t hbuf[2][HH];
  __shared__ float gsum[G3];

  // W: full row tid of Whh, 128 packed f16-pairs = 8 x uint16v = 128 VGPRs
  uint16v W[8];
  {
    const uint4* wp = (const uint4*)(Whhh + (size_t)tid * HH);
    #pragma unroll
    for (int j = 0; j < 32; ++j) {
      uint4 v = wp[j];
      int base = 4 * j;  // constant after unroll
      W[base >> 4][(base & 15) + 0] = v.x;
      W[base >> 4][(base & 15) + 1] = v.y;
      W[base >> 4][(base & 15) + 2] = v.z;
      W[base >> 4][(base & 15) + 3] = v.w;
    }
  }

  const int len = slen[b];
  float bhn = 0.f, hold = 0.f;
  if (tid < HH) {
    bhn = bhh[2 * HH + tid];
    hbuf[0][tid] = (half_t)0.f;
    hbuf[1][tid] = (half_t)0.f;
  }
  __syncthreads();

  const float* gib = gi + (size_t)b * G3;
  float* outb = out + (size_t)b * HH;

  #pragma unroll 1
  for (int t = 0; t < LL; ++t) {
    const int p = t & 1;
    float g0 = 0.f, g1 = 0.f, g2 = 0.f;
    if (tid < HH) {
      const float* gp = gib + (size_t)t * (BB * G3);
      g0 = gp[tid]; g1 = gp[HH + tid]; g2 = gp[2 * HH + tid];
    }
    float accA = 0.f, accB = 0.f;
    const uint4* hb = (const uint4*)hbuf[p];
    #pragma unroll
    for (int j = 0; j < 32; ++j) {
      uint4 hc = hb[j];                 // same addr across wave: broadcast
      int i0 = 4 * j;                   // constant after unroll
      unsigned int w0 = W[i0 >> 4][(i0 & 15) + 0];
      unsigned int w1 = W[i0 >> 4][(i0 & 15) + 1];
      unsigned int w2 = W[i0 >> 4][(i0 & 15) + 2];
      unsigned int w3 = W[i0 >> 4][(i0 & 15) + 3];
      if (j & 1) {
        accB = fdot2u(w0, hc.x, accB);
        accB = fdot2u(w1, hc.y, accB);
        accB = fdot2u(w2, hc.z, accB);
        accB = fdot2u(w3, hc.w, accB);
      } else {
        accA = fdot2u(w0, hc.x, accA);
        accA = fdot2u(w1, hc.y, accA);
        accA = fdot2u(w2, hc.z, accA);
        accA = fdot2u(w3, hc.w, accA);
      }
    }
    gsum[tid] = accA + accB;
    BARRIER_LDS();
    if (tid < HH) {
      float r_ = sigmoidf_(g0 + gsum[tid]);
      float z_ = sigmoidf_(g1 + gsum[HH + tid]);
      float n_ = tanhf_(g2 + r_ * (gsum[2 * HH + tid] + bhn));
      float hnew = (1.f - z_) * n_ + z_ * hold;
      bool valid = t < len;
      hold = valid ? hnew : hold;
      hbuf[p ^ 1][tid] = (half_t)hold;
      outb[(size_t)t * (BB * HH) + tid] = valid ? hnew : 0.f;
    }
    BARRIER_LDS();
  }
  if (tid < HH) hT[(size_t)b * HH + tid] = hold;
}

// ---------------------------------------------------------------------------
// ctx[b, h*256+d] = sum_l wsoft[l,b,h] * out1[l,b,d]
// ---------------------------------------------------------------------------
__global__ void ctx_kernel(
    const float* __restrict__ wsoft, const float* __restrict__ out1,
    float* __restrict__ ctx)
{
  int b = blockIdx.x >> 3, h = blockIdx.x & 7;
  int d = threadIdx.x;  // 256
  float acc = 0.f;
  for (int l = 0; l < LL; ++l) {
    float w = wsoft[((size_t)l * BB + b) * NHH + h];
    acc += w * out1[((size_t)l * BB + b) * HH + d];
  }
  ctx[(size_t)b * (NHH * HH) + h * HH + d] = acc;
}

// ---------------------------------------------------------------------------
// final MLP: z = selu([ctx, hT] @ Wf0.T + bf0); logits = z @ Wf1.T + bf1;
// out = log_softmax(logits)
// ---------------------------------------------------------------------------
__global__ __launch_bounds__(512) void final_kernel(
    const float* __restrict__ ctx, const float* __restrict__ hT,
    const float* __restrict__ Wf0,   // [168][2304]
    const float* __restrict__ bf0,
    const float* __restrict__ Wf1,   // [100][168]
    const float* __restrict__ bf1,
    float* __restrict__ outp)        // [B][100]
{
  int b = blockIdx.x;
  int tid = threadIdx.x;
  int wave = tid >> 6, lane = tid & 63;
  __shared__ float4 xs4[CLSIN / 4];
  __shared__ float zs[F1];
  __shared__ float ls[ETA];
  float* xs = (float*)xs4;
  for (int i = tid; i < NHH * HH; i += 512) xs[i] = ctx[(size_t)b * (NHH * HH) + i];
  if (tid < HH) xs[NHH * HH + tid] = hT[(size_t)b * HH + tid];
  __syncthreads();
  for (int r = wave; r < F1; r += 8) {
    const float4* wp = (const float4*)(Wf0 + (size_t)r * CLSIN);
    float acc = 0.f;
    #pragma unroll
    for (int i = 0; i < CLSIN / 4 / 64; ++i) {  // 9
      float4 w = wp[lane + 64 * i];
      float4 x = xs4[lane + 64 * i];
      acc += w.x * x.x + w.y * x.y + w.z * x.z + w.w * x.w;
    }
    #pragma unroll
    for (int off = 32; off > 0; off >>= 1) acc += __shfl_xor(acc, off, 64);
    if (lane == 0) {
      float x = acc + bf0[r];
      const float alpha = 1.6732632423543772f, scale = 1.0507009873554805f;
      zs[r] = scale * (x > 0.f ? x : alpha * (__expf(x) - 1.f));
    }
  }
  __syncthreads();
  for (int r = wave; r < ETA; r += 8) {
    float acc = 0.f;
    for (int k = lane; k < F1; k += 64) acc += Wf1[r * F1 + k] * zs[k];
    #pragma unroll
    for (int off = 32; off > 0; off >>= 1) acc += __shfl_xor(acc, off, 64);
    if (lane == 0) ls[r] = acc + bf1[r];
  }
  __syncthreads();
  if (wave == 0) {
    float v0 = (lane < ETA) ? ls[lane] : -1e30f;
    float v1 = (lane + 64 < ETA) ? ls[lane + 64] : -1e30f;
    float m = fmaxf(v0, v1);
    #pragma unroll
    for (int off = 32; off > 0; off >>= 1) m = fmaxf(m, __shfl_xor(m, off, 64));
    float s = __expf(v0 - m) + __expf(v1 - m);
    #pragma unroll
    for (int off = 32; off > 0; off >>= 1) s += __shfl_xor(s, off, 64);
    float lse = m + __logf(s);
    if (lane < ETA) outp[(size_t)b * ETA + lane] = v0 - lse;
    if (lane + 64 < ETA) outp[(size_t)b * ETA + lane + 64] = v1 - lse;
  }
}

extern "C" void kernel_launch(void* const* d_in, const int* in_sizes, int n_in,
                              void* d_out, int out_size, void* d_ws, size_t ws_size,
                              hipStream_t stream) {
  const int*   node  = (const int*)d_in[0];
  const float* ts    = (const float*)d_in[1];
  const int*   slen  = (const int*)d_in[2];
  const float* table = (const float*)d_in[3];
  const float* Wih0  = (const float*)d_in[4];
  const float* Whh0  = (const float*)d_in[5];
  const float* bih0  = (const float*)d_in[6];
  const float* bhh0  = (const float*)d_in[7];
  const float* Wih1  = (const float*)d_in[8];
  const float* Whh1  = (const float*)d_in[9];
  const float* bih1  = (const float*)d_in[10];
  const float* bhh1  = (const float*)d_in[11];
  const float* Wa0   = (const float*)d_in[12];
  const float* ba0   = (const float*)d_in[13];
  const float* Wa1   = (const float*)d_in[14];
  const float* ba1   = (const float*)d_in[15];
  const float* Wf0   = (const float*)d_in[16];
  const float* bf0   = (const float*)d_in[17];
  const float* Wf1   = (const float*)d_in[18];
  const float* bf1   = (const float*)d_in[19];

  char* ws = (char*)d_ws;
  size_t off = 0;
  auto alloc = [&](size_t n) { void* p = (void*)(ws + off); off += (n + 255) & ~(size_t)255; return p; };

  half2v* e_h2 = (half2v*)alloc((size_t)LL * BB * 64 * 4);
  float* U     = (float*)alloc((size_t)LL * BB * EE * 4);
  float* V     = (float*)alloc((size_t)LL * BB * EE * 4);
  float* gi    = (float*)alloc((size_t)LL * BB * G3 * 4);   // reused for both layers
  float* out0  = (float*)alloc((size_t)LL * BB * HH * 4);
  float* out1  = (float*)alloc((size_t)LL * BB * HH * 4);
  float* hTb   = (float*)alloc((size_t)BB * HH * 4);
  float* wpre  = (float*)alloc((size_t)LL * BB * NHH * 4);
  float* wsoft = (float*)alloc((size_t)LL * BB * NHH * 4);
  float* ctxb  = (float*)alloc((size_t)BB * NHH * HH * 4);
  half_t* Wa0Ta = (half_t*)alloc((size_t)128 * 128 * 2);
  half_t* Wa0Tb = (half_t*)alloc((size_t)128 * 128 * 2);
  half2v* Wih0T2 = (half2v*)alloc((size_t)65 * 768 * 4);
  half2v* Wih1T2 = (half2v*)alloc((size_t)128 * 768 * 4);
  half_t* Whh0h = (half_t*)alloc((size_t)G3 * HH * 2);
  half_t* Whh1h = (half_t*)alloc((size_t)G3 * HH * 2);
  if (off > ws_size) return;  // workspace too small: fail visibly

  const int prep_total = 16384 + 16384 + 65 * 768 + 128 * 768 + 196608 + 196608;
  prep_kernel<<<(prep_total + 255) / 256, 256, 0, stream>>>(
      Wa0, Wih0, Wih1, Whh0, Whh1, Wa0Ta, Wa0Tb, Wih0T2, Wih1T2, Whh0h, Whh1h);
  embed_uv_kernel<<<LL * BB, 128, 0, stream>>>(node, table, Wa0Ta, Wa0Tb, ba0, e_h2, U, V);
  attn_w_kernel<<<(LL / 4) * BB, 128, 0, stream>>>(U, V, Wa1, ba1, wpre);
  attn_softmax_kernel<<<BB * NHH, 128, 0, stream>>>(wpre, slen, wsoft);
  gi0_kernel<<<LL * BB / 8, 256, 0, stream>>>(e_h2, ts, Wih0T2, bih0, bhh0, gi);
  gru_scan_kernel<<<BB, 768, 0, stream>>>(Whh0h, bhh0, gi, slen, out0, hTb);
  gi1_kernel<<<LL * BB / 8, 256, 0, stream>>>(out0, Wih1T2, bih1, bhh1, gi);
  gru_scan_kernel<<<BB, 768, 0, stream>>>(Whh1h, bhh1, gi, slen, out1, hTb);
  ctx_kernel<<<BB * NHH, 256, 0, stream>>>(wsoft, out1, ctxb);
  final_kernel<<<BB, 512, 0, stream>>>(ctxb, hTb, Wf0, bf0, Wf1, bf1, (float*)d_out);
}